// Round 9
// baseline (350.655 us; speedup 1.0000x reference)
//
#include <hip/hip_runtime.h>
#include <math.h>

#define BB 4
#define CC 128
#define BT 32
#define NBOX 4
#define HH 256
#define WW 256
#define HW (HH*WW)
#define SP 257
#define SPLANE (SP*SP)
#define NPLANE (BB*BT)          // 128 integral-image planes
#define CHUNK 32                // rows per column-scan chunk
#define NCHUNK (HH/CHUNK)       // 8
#define ROWS 16                 // output rows per box_sample block
#define KW 8                    // output channels per wave (32 = 4 waves x 8)

// ---------------- Kernel A: 1x1 conv (128->32) + BN1 + row inclusive scan ----------------
// k-split across waves: all 4 waves of a block process the SAME image row
// (float4 per lane, identical x addresses -> wave 0 misses, waves 1-3 hit L1/L2,
// FETCH unchanged), each wave owns 8 of the 32 output channels. This lifts
// waves/SIMD from 1 (r6: 1024 rows x 1 wave/row) to 4 with NO extra x traffic
// (unlike r5's x-channel split which doubled FETCH) and NO association change:
// every (k,px) FMA chain (c ascending), BN1, scan, and store are bit-identical
// to round 6 (passed @ absmax 0.015625). acc[8]x4 = 32 VGPR -> ~64 total, no
// allocator pressure (r7's unroll-8 pushed acc out of VGPRs: VGPR_Count=92 < 128
// needed -> 98us). unroll 4 = the r6-proven window. No LDS, no barrier.
__global__ __launch_bounds__(256) void conv_bn1_scan(
        const float* __restrict__ x, const float* __restrict__ w1,
        const float* __restrict__ g1, const float* __restrict__ b1,
        const float* __restrict__ m1, const float* __restrict__ v1,
        float* __restrict__ t) {
    int gr   = blockIdx.x;              // global row: b*HH + i
    int wave = threadIdx.x >> 6;        // k-octet index
    int lane = threadIdx.x & 63;        // column quad
    int b      = gr >> 8;
    int rowpix = (gr & 255) * WW;
    const float4* xb = (const float4*)(x + (size_t)b * (CC * HW) + rowpix) + lane;
    const float* wbase = w1 + (wave * KW) * CC;

    float4 acc[KW];
    #pragma unroll
    for (int k = 0; k < KW; ++k) acc[k] = make_float4(0.f, 0.f, 0.f, 0.f);

    #pragma unroll 4
    for (int c = 0; c < CC; ++c) {
        float4 xv = xb[c * (HW / 4)];
        #pragma unroll
        for (int k = 0; k < KW; ++k) {
            float wv = wbase[k * CC + c];
            acc[k].x = fmaf(xv.x, wv, acc[k].x);
            acc[k].y = fmaf(xv.y, wv, acc[k].y);
            acc[k].z = fmaf(xv.z, wv, acc[k].z);
            acc[k].w = fmaf(xv.w, wv, acc[k].w);
        }
    }

    // BN1 (must precede the scan: reference scans bn1(conv) output)
    #pragma unroll
    for (int k = 0; k < KW; ++k) {
        int k0 = wave * KW + k;
        float inv = g1[k0] * __frsqrt_rn(v1[k0] + 1e-5f);
        float add = b1[k0] - m1[k0] * inv;
        acc[k].x = acc[k].x * inv + add;
        acc[k].y = acc[k].y * inv + add;
        acc[k].z = acc[k].z * inv + add;
        acc[k].w = acc[k].w * inv + add;
    }

    // per-wave row scan: in-thread prefix over 4, then 64-lane shfl scan
    float4* tb = (float4*)(t + (size_t)b * (BT * HW) + (size_t)(wave * KW) * HW
                           + rowpix) + lane;
    #pragma unroll
    for (int k = 0; k < KW; ++k) {
        float4 v = acc[k];
        v.y += v.x; v.z += v.y; v.w += v.z;
        float tot = v.w;
        float sum = tot;
        #pragma unroll
        for (int off = 1; off < 64; off <<= 1) {
            float o = __shfl_up(sum, off, 64);
            if (lane >= off) sum += o;
        }
        float excl = sum - tot;
        v.x += excl; v.y += excl; v.z += excl; v.w += excl;
        tb[k * (HW / 4)] = v;
    }
}

// ---------------- Kernel B2a: per-chunk column partial sums (float4 cols) ----------------
// grid = NPLANE*NCHUNK blocks of 64; thread = column quad (4 cols via float4).
// Per-component accumulate order over r identical to the scalar version -> bitwise same.
__global__ __launch_bounds__(64) void col_partial(const float* __restrict__ t,
                                                  float* __restrict__ T) {
    int plane = blockIdx.x >> 3;
    int chunk = blockIdx.x & 7;
    int q = threadIdx.x;                 // col quad: cols 4q..4q+3
    const float4* tp = (const float4*)(t + (size_t)plane * HW + chunk * CHUNK * WW) + q;
    float4 vals[CHUNK];
    #pragma unroll
    for (int r = 0; r < CHUNK; ++r) vals[r] = tp[r * (WW / 4)];
    float4 s = make_float4(0.f, 0.f, 0.f, 0.f);
    #pragma unroll
    for (int r = 0; r < CHUNK; ++r) {
        s.x += vals[r].x; s.y += vals[r].y; s.z += vals[r].z; s.w += vals[r].w;
    }
    ((float4*)(T + blockIdx.x * 256))[q] = s;
}

// ---------------- Kernel B2b: column scan with chunk offsets -> padded S ----------------
// grid = NPLANE*NCHUNK blocks of 64; thread = column quad. float4 loads of T and h;
// stores to S stay scalar (the +1 padding column misaligns 16B). Per-component
// order identical to the scalar version.
__global__ __launch_bounds__(64) void col_final(const float* __restrict__ t,
                                                const float* __restrict__ T,
                                                float* __restrict__ s) {
    int plane = blockIdx.x >> 3;
    int chunk = blockIdx.x & 7;
    int q = threadIdx.x;                 // col quad: cols 4q..4q+3
    float4 off = make_float4(0.f, 0.f, 0.f, 0.f);
    for (int c = 0; c < chunk; ++c) {
        float4 tv = ((const float4*)(T + (plane * 8 + c) * 256))[q];
        off.x += tv.x; off.y += tv.y; off.z += tv.z; off.w += tv.w;
    }
    const float4* tp = (const float4*)(t + (size_t)plane * HW + chunk * CHUNK * WW) + q;
    float* sp = s + (size_t)plane * SPLANE;
    if (chunk == 0) {                    // top padding row
        #pragma unroll
        for (int e = 0; e < 4; ++e) sp[4 * q + 1 + e] = 0.f;
        if (q == 0) sp[0] = 0.f;
    }
    float4 vals[CHUNK];
    #pragma unroll
    for (int r = 0; r < CHUNK; ++r) vals[r] = tp[r * (WW / 4)];
    float4 run = off;
    int rowbase = chunk * CHUNK;
    #pragma unroll
    for (int r = 0; r < CHUNK; ++r) {
        run.x += vals[r].x; run.y += vals[r].y; run.z += vals[r].z; run.w += vals[r].w;
        float* row = sp + (size_t)(rowbase + r + 1) * SP;
        row[4 * q + 1] = run.x;
        row[4 * q + 2] = run.y;
        row[4 * q + 3] = run.z;
        row[4 * q + 4] = run.w;
        if (q == 0) row[0] = 0.f;        // left padding col
    }
}

// ---------------- Kernel C: box sample via shared D-rows + BN2 + relus ----------------
// grid = B*BT*NBOX*(H/ROWS) blocks; each block produces ROWS=16 output rows.
// Each wave builds 4 D-rows into LDS; each thread then emits 16 elements at
// column j, amortizing horizontal setup + BN2 scalars 16x. The 16 x-values are
// prefetched into registers BEFORE the barrier so their HBM latency hides under
// the D-row build (T14 pattern). Near HBM floor (~313MB traffic).
__global__ __launch_bounds__(256) void box_sample(
        const float* __restrict__ s, const float* __restrict__ x,
        const float* __restrict__ xmin, const float* __restrict__ xmax,
        const float* __restrict__ ymin, const float* __restrict__ ymax,
        const float* __restrict__ g2, const float* __restrict__ b2,
        const float* __restrict__ m2, const float* __restrict__ v2,
        float* __restrict__ out) {
    __shared__ float D[ROWS][SP];
    int bid = blockIdx.x;
    int ig = bid & 15;                   // H/ROWS = 16 row-groups
    int n  = (bid >> 4) & 3;
    int k  = (bid >> 6) & 31;
    int b  = bid >> 11;
    int j  = threadIdx.x;
    int lane = j & 63;
    int wave = j >> 6;
    int kn = k * NBOX + n;
    int ibase = ig * ROWS;
    const float* sp = s + (size_t)(b * BT + k) * SPLANE;

    float xmn = xmin[kn], xmx = xmax[kn], ymn = ymin[kn], ymx = ymax[kn];

    // prefetch x for all 16 rows at this column (independent of D-build)
    int obase = ((b * CC + kn) * HH + ibase) * WW + j;   // < 2^25, fits int
    const float* xp = x + obase;
    float xv[ROWS];
    #pragma unroll
    for (int r = 0; r < ROWS; ++r) xv[r] = __builtin_nontemporal_load(xp + r * WW);

    // Each wave builds D rows {wave, wave+4, wave+8, wave+12}
    #pragma unroll
    for (int rr = 0; rr < 4; ++rr) {
        int r = wave + rr * 4;
        float fi = (float)(ibase + r);
        float u_hi = fminf(fmaxf(fi + xmx, 0.f), 256.f);
        float u_lo = fminf(fmaxf(fi + xmn, 0.f), 256.f);
        int i1 = (int)fminf(floorf(u_hi), 255.f);
        int i0 = (int)fminf(floorf(u_lo), 255.f);
        float wu1 = u_hi - (float)i1;
        float wu0 = u_lo - (float)i0;
        const float* rA = sp + (size_t)i1 * SP;
        const float* rB = rA + SP;
        const float* rC = sp + (size_t)i0 * SP;
        const float* rD = rC + SP;
        #pragma unroll
        for (int tcol = 0; tcol < 4; ++tcol) {
            int c = lane + tcol * 64;
            D[r][c] = rA[c] * (1.f - wu1) + rB[c] * wu1
                    - rC[c] * (1.f - wu0) - rD[c] * wu0;
        }
        if (lane == 0) {
            int c = 256;
            D[r][c] = rA[c] * (1.f - wu1) + rB[c] * wu1
                    - rC[c] * (1.f - wu0) - rD[c] * wu0;
        }
    }
    __syncthreads();

    // horizontal setup: once per thread, reused for all 16 rows
    float v_hi = fminf(fmaxf((float)j + ymx, 0.f), 256.f);
    float v_lo = fminf(fmaxf((float)j + ymn, 0.f), 256.f);
    int j1 = (int)fminf(floorf(v_hi), 255.f);
    int j0 = (int)fminf(floorf(v_lo), 255.f);
    float wv1 = v_hi - (float)j1;
    float wv0 = v_lo - (float)j0;
    float cv1 = 1.f - wv1;
    float cv0 = 1.f - wv0;

    float inv = g2[kn] * __frsqrt_rn(v2[kn] + 1e-3f);
    float scale = inv * __frcp_rn((xmx - xmn) * (ymx - ymn));
    float add = b2[kn] - m2[kn] * inv;

    float* op = out + obase;
    #pragma unroll
    for (int r = 0; r < ROWS; ++r) {
        float hi = D[r][j1] * cv1 + D[r][j1 + 1] * wv1;
        float lo = D[r][j0] * cv0 + D[r][j0 + 1] * wv0;
        float val = (hi - lo) * scale + add;
        val = fmaxf(val, 0.f);                            // relu(bn2)
        __builtin_nontemporal_store(fmaxf(xv[r] + val, 0.f), op + r * WW);
    }
}

extern "C" void kernel_launch(void* const* d_in, const int* in_sizes, int n_in,
                              void* d_out, int out_size, void* d_ws, size_t ws_size,
                              hipStream_t stream) {
    const float* x    = (const float*)d_in[0];
    const float* w1   = (const float*)d_in[1];
    const float* g1   = (const float*)d_in[2];
    const float* b1   = (const float*)d_in[3];
    const float* m1   = (const float*)d_in[4];
    const float* v1   = (const float*)d_in[5];
    const float* xmin = (const float*)d_in[6];
    const float* xmax = (const float*)d_in[7];
    const float* ymin = (const float*)d_in[8];
    const float* ymax = (const float*)d_in[9];
    const float* g2   = (const float*)d_in[10];
    const float* b2   = (const float*)d_in[11];
    const float* m2   = (const float*)d_in[12];
    const float* v2   = (const float*)d_in[13];
    float* out = (float*)d_out;

    float* h = (float*)d_ws;                        // B*BT*HW floats (33.5 MB), row-scanned
    float* S = h + (size_t)BB * BT * HW;            // NPLANE*SPLANE floats (33.8 MB)
    float* T = S + (size_t)NPLANE * SPLANE;         // NPLANE*NCHUNK*256 floats (1 MB)

    conv_bn1_scan<<<BB * HH, 256, 0, stream>>>(x, w1, g1, b1, m1, v1, h);
    col_partial  <<<NPLANE * NCHUNK, 64, 0, stream>>>(h, T);
    col_final    <<<NPLANE * NCHUNK, 64, 0, stream>>>(h, T, S);
    box_sample   <<<BB * BT * NBOX * (HH / ROWS), 256, 0, stream>>>(
                     S, x, xmin, xmax, ymin, ymax, g2, b2, m2, v2, out);
}

// Round 10
// 346.916 us; speedup vs baseline: 1.0108x; 1.0108x over previous
//
#include <hip/hip_runtime.h>
#include <math.h>

#define BB 4
#define CC 128
#define BT 32
#define NBOX 4
#define HH 256
#define WW 256
#define HW (HH*WW)
#define SP 257
#define SPLANE (SP*SP)
#define NPLANE (BB*BT)          // 128 integral-image planes
#define CHUNK 32                // rows per column-scan chunk
#define NCHUNK (HH/CHUNK)       // 8
#define ROWS 16                 // output rows per box_sample block

// ---------------- Kernel A: 1x1 conv (128->32) + BN1 + row inclusive scan ----------------
// r6 structure (float4 over pixels, wave = one row, all 32 k) with the allocator
// unshackled: __launch_bounds__(256,1) raises the VGPR cap to ~512, ABOVE the
// ~180 demand (acc[32]x4=128 + 8-float4 window + addressing). Evidence: r7's
// unroll-8 got VGPR_Count=92 (< the 128 acc needs -> serialized loads); r9 got 44.
// The allocator targets occupancy unless told otherwise; here grid = 256 blocks
// = 1 wave/SIMD regardless, so occupancy is structurally free. unroll 8 keeps
// 8 loads (8KB/wave) in flight; compute per window = 2048cy > ~1200cy latency.
// FMA order (c ascending, k inner, 4 comps), BN1, scan, store bit-identical to
// round 6 (passed @ absmax 0.015625).
__global__ __launch_bounds__(256, 1) void conv_bn1_scan(
        const float* __restrict__ x, const float* __restrict__ w1,
        const float* __restrict__ g1, const float* __restrict__ b1,
        const float* __restrict__ m1, const float* __restrict__ v1,
        float* __restrict__ t) {
    int p4 = blockIdx.x * 1024 + threadIdx.x * 4;   // first pixel of this thread's quad
    int b  = p4 >> 16;
    int ij = p4 & 65535;
    const float4* xb = (const float4*)(x + (size_t)b * (CC * HW) + ij);   // + c*(HW/4)
    float4 acc[BT];
    #pragma unroll
    for (int k = 0; k < BT; ++k) acc[k] = make_float4(0.f, 0.f, 0.f, 0.f);

    #pragma unroll 8
    for (int c = 0; c < CC; ++c) {
        float4 xv = xb[c * (HW / 4)];
        #pragma unroll
        for (int k = 0; k < BT; ++k) {
            float wv = w1[k * CC + c];
            acc[k].x = fmaf(xv.x, wv, acc[k].x);
            acc[k].y = fmaf(xv.y, wv, acc[k].y);
            acc[k].z = fmaf(xv.z, wv, acc[k].z);
            acc[k].w = fmaf(xv.w, wv, acc[k].w);
        }
    }

    // BN1 (must precede the scan: reference scans bn1(conv) output)
    #pragma unroll
    for (int k = 0; k < BT; ++k) {
        float inv = g1[k] * __frsqrt_rn(v1[k] + 1e-5f);
        float add = b1[k] - m1[k] * inv;
        acc[k].x = acc[k].x * inv + add;
        acc[k].y = acc[k].y * inv + add;
        acc[k].z = acc[k].z * inv + add;
        acc[k].w = acc[k].w * inv + add;
    }

    // per-wave row scan: in-thread prefix over 4, then 64-lane shfl scan
    int lane = threadIdx.x & 63;
    float4* tb = (float4*)(t + (size_t)b * (BT * HW) + ij);               // + k*(HW/4)
    #pragma unroll
    for (int k = 0; k < BT; ++k) {
        float4 v = acc[k];
        v.y += v.x; v.z += v.y; v.w += v.z;
        float tot = v.w;
        float sum = tot;
        #pragma unroll
        for (int off = 1; off < 64; off <<= 1) {
            float o = __shfl_up(sum, off, 64);
            if (lane >= off) sum += o;
        }
        float excl = sum - tot;
        v.x += excl; v.y += excl; v.z += excl; v.w += excl;
        tb[k * (HW / 4)] = v;
    }
}

// ---------------- Kernel B2a: per-chunk column partial sums (float4 cols) ----------------
// grid = NPLANE*NCHUNK blocks of 64; thread = column quad (4 cols via float4).
// Per-component accumulate order over r identical to the scalar version -> bitwise same.
__global__ __launch_bounds__(64) void col_partial(const float* __restrict__ t,
                                                  float* __restrict__ T) {
    int plane = blockIdx.x >> 3;
    int chunk = blockIdx.x & 7;
    int q = threadIdx.x;                 // col quad: cols 4q..4q+3
    const float4* tp = (const float4*)(t + (size_t)plane * HW + chunk * CHUNK * WW) + q;
    float4 vals[CHUNK];
    #pragma unroll
    for (int r = 0; r < CHUNK; ++r) vals[r] = tp[r * (WW / 4)];
    float4 s = make_float4(0.f, 0.f, 0.f, 0.f);
    #pragma unroll
    for (int r = 0; r < CHUNK; ++r) {
        s.x += vals[r].x; s.y += vals[r].y; s.z += vals[r].z; s.w += vals[r].w;
    }
    ((float4*)(T + blockIdx.x * 256))[q] = s;
}

// ---------------- Kernel B2b: column scan with chunk offsets -> padded S ----------------
// grid = NPLANE*NCHUNK blocks of 64; thread = column quad. float4 loads of T and h;
// stores to S stay scalar (the +1 padding column misaligns 16B). Per-component
// order identical to the scalar version.
__global__ __launch_bounds__(64) void col_final(const float* __restrict__ t,
                                                const float* __restrict__ T,
                                                float* __restrict__ s) {
    int plane = blockIdx.x >> 3;
    int chunk = blockIdx.x & 7;
    int q = threadIdx.x;                 // col quad: cols 4q..4q+3
    float4 off = make_float4(0.f, 0.f, 0.f, 0.f);
    for (int c = 0; c < chunk; ++c) {
        float4 tv = ((const float4*)(T + (plane * 8 + c) * 256))[q];
        off.x += tv.x; off.y += tv.y; off.z += tv.z; off.w += tv.w;
    }
    const float4* tp = (const float4*)(t + (size_t)plane * HW + chunk * CHUNK * WW) + q;
    float* sp = s + (size_t)plane * SPLANE;
    if (chunk == 0) {                    // top padding row
        #pragma unroll
        for (int e = 0; e < 4; ++e) sp[4 * q + 1 + e] = 0.f;
        if (q == 0) sp[0] = 0.f;
    }
    float4 vals[CHUNK];
    #pragma unroll
    for (int r = 0; r < CHUNK; ++r) vals[r] = tp[r * (WW / 4)];
    float4 run = off;
    int rowbase = chunk * CHUNK;
    #pragma unroll
    for (int r = 0; r < CHUNK; ++r) {
        run.x += vals[r].x; run.y += vals[r].y; run.z += vals[r].z; run.w += vals[r].w;
        float* row = sp + (size_t)(rowbase + r + 1) * SP;
        row[4 * q + 1] = run.x;
        row[4 * q + 2] = run.y;
        row[4 * q + 3] = run.z;
        row[4 * q + 4] = run.w;
        if (q == 0) row[0] = 0.f;        // left padding col
    }
}

// ---------------- Kernel C: box sample via shared D-rows + BN2 + relus ----------------
// grid = B*BT*NBOX*(H/ROWS) blocks; each block produces ROWS=16 output rows.
// Each wave builds 4 D-rows into LDS; each thread then emits 16 elements at
// column j, amortizing horizontal setup + BN2 scalars 16x. The 16 x-values are
// prefetched into registers BEFORE the barrier so their HBM latency hides under
// the D-row build (T14 pattern). Near HBM floor (~313MB traffic @ ~5 TB/s).
__global__ __launch_bounds__(256) void box_sample(
        const float* __restrict__ s, const float* __restrict__ x,
        const float* __restrict__ xmin, const float* __restrict__ xmax,
        const float* __restrict__ ymin, const float* __restrict__ ymax,
        const float* __restrict__ g2, const float* __restrict__ b2,
        const float* __restrict__ m2, const float* __restrict__ v2,
        float* __restrict__ out) {
    __shared__ float D[ROWS][SP];
    int bid = blockIdx.x;
    int ig = bid & 15;                   // H/ROWS = 16 row-groups
    int n  = (bid >> 4) & 3;
    int k  = (bid >> 6) & 31;
    int b  = bid >> 11;
    int j  = threadIdx.x;
    int lane = j & 63;
    int wave = j >> 6;
    int kn = k * NBOX + n;
    int ibase = ig * ROWS;
    const float* sp = s + (size_t)(b * BT + k) * SPLANE;

    float xmn = xmin[kn], xmx = xmax[kn], ymn = ymin[kn], ymx = ymax[kn];

    // prefetch x for all 16 rows at this column (independent of D-build)
    int obase = ((b * CC + kn) * HH + ibase) * WW + j;   // < 2^25, fits int
    const float* xp = x + obase;
    float xv[ROWS];
    #pragma unroll
    for (int r = 0; r < ROWS; ++r) xv[r] = __builtin_nontemporal_load(xp + r * WW);

    // Each wave builds D rows {wave, wave+4, wave+8, wave+12}
    #pragma unroll
    for (int rr = 0; rr < 4; ++rr) {
        int r = wave + rr * 4;
        float fi = (float)(ibase + r);
        float u_hi = fminf(fmaxf(fi + xmx, 0.f), 256.f);
        float u_lo = fminf(fmaxf(fi + xmn, 0.f), 256.f);
        int i1 = (int)fminf(floorf(u_hi), 255.f);
        int i0 = (int)fminf(floorf(u_lo), 255.f);
        float wu1 = u_hi - (float)i1;
        float wu0 = u_lo - (float)i0;
        const float* rA = sp + (size_t)i1 * SP;
        const float* rB = rA + SP;
        const float* rC = sp + (size_t)i0 * SP;
        const float* rD = rC + SP;
        #pragma unroll
        for (int tcol = 0; tcol < 4; ++tcol) {
            int c = lane + tcol * 64;
            D[r][c] = rA[c] * (1.f - wu1) + rB[c] * wu1
                    - rC[c] * (1.f - wu0) - rD[c] * wu0;
        }
        if (lane == 0) {
            int c = 256;
            D[r][c] = rA[c] * (1.f - wu1) + rB[c] * wu1
                    - rC[c] * (1.f - wu0) - rD[c] * wu0;
        }
    }
    __syncthreads();

    // horizontal setup: once per thread, reused for all 16 rows
    float v_hi = fminf(fmaxf((float)j + ymx, 0.f), 256.f);
    float v_lo = fminf(fmaxf((float)j + ymn, 0.f), 256.f);
    int j1 = (int)fminf(floorf(v_hi), 255.f);
    int j0 = (int)fminf(floorf(v_lo), 255.f);
    float wv1 = v_hi - (float)j1;
    float wv0 = v_lo - (float)j0;
    float cv1 = 1.f - wv1;
    float cv0 = 1.f - wv0;

    float inv = g2[kn] * __frsqrt_rn(v2[kn] + 1e-3f);
    float scale = inv * __frcp_rn((xmx - xmn) * (ymx - ymn));
    float add = b2[kn] - m2[kn] * inv;

    float* op = out + obase;
    #pragma unroll
    for (int r = 0; r < ROWS; ++r) {
        float hi = D[r][j1] * cv1 + D[r][j1 + 1] * wv1;
        float lo = D[r][j0] * cv0 + D[r][j0 + 1] * wv0;
        float val = (hi - lo) * scale + add;
        val = fmaxf(val, 0.f);                            // relu(bn2)
        __builtin_nontemporal_store(fmaxf(xv[r] + val, 0.f), op + r * WW);
    }
}

extern "C" void kernel_launch(void* const* d_in, const int* in_sizes, int n_in,
                              void* d_out, int out_size, void* d_ws, size_t ws_size,
                              hipStream_t stream) {
    const float* x    = (const float*)d_in[0];
    const float* w1   = (const float*)d_in[1];
    const float* g1   = (const float*)d_in[2];
    const float* b1   = (const float*)d_in[3];
    const float* m1   = (const float*)d_in[4];
    const float* v1   = (const float*)d_in[5];
    const float* xmin = (const float*)d_in[6];
    const float* xmax = (const float*)d_in[7];
    const float* ymin = (const float*)d_in[8];
    const float* ymax = (const float*)d_in[9];
    const float* g2   = (const float*)d_in[10];
    const float* b2   = (const float*)d_in[11];
    const float* m2   = (const float*)d_in[12];
    const float* v2   = (const float*)d_in[13];
    float* out = (float*)d_out;

    float* h = (float*)d_ws;                        // B*BT*HW floats (33.5 MB), row-scanned
    float* S = h + (size_t)BB * BT * HW;            // NPLANE*SPLANE floats (33.8 MB)
    float* T = S + (size_t)NPLANE * SPLANE;         // NPLANE*NCHUNK*256 floats (1 MB)

    conv_bn1_scan<<<(BB * HW) / 1024, 256, 0, stream>>>(x, w1, g1, b1, m1, v1, h);
    col_partial  <<<NPLANE * NCHUNK, 64, 0, stream>>>(h, T);
    col_final    <<<NPLANE * NCHUNK, 64, 0, stream>>>(h, T, S);
    box_sample   <<<BB * BT * NBOX * (HH / ROWS), 256, 0, stream>>>(
                     S, x, xmin, xmax, ymin, ymax, g2, b2, m2, v2, out);
}

// Round 13
// 343.321 us; speedup vs baseline: 1.0214x; 1.0105x over previous
//
#include <hip/hip_runtime.h>
#include <math.h>

#define BB 4
#define CC 128
#define BT 32
#define NBOX 4
#define HH 256
#define WW 256
#define HW (HH*WW)
#define SP 257
#define SPLANE (SP*SP)
#define NPLANE (BB*BT)          // 128 integral-image planes
#define CHUNK 32                // rows per column-scan chunk
#define NCHUNK (HH/CHUNK)       // 8
#define ROWS 16                 // output rows per box_sample block

// ---------------- Kernel A: 1x1 conv (128->32) + BN1 + row inclusive scan ----------------
// Exact r6 structure (float4 over pixels, wave = one row, all 32 k, unroll 4 -
// best-measured conv, 78us) with ONE change: weights staged TRANSPOSED into LDS
// (wLDS[c*32+k]) at kernel start, so each c-iteration reads 32 CONTIGUOUS words
// via broadcast ds_read instead of 32 stride-512B unmergeable s_load_dword -
// the serial scalar chain every conv variant r1-r10 shared (all 78-107us
// regardless of occupancy/ILP; r10 refuted the VGPR-cap theory).
// Staging: dest-contiguous LDS writes (conflict-free); scattered 16KB global
// reads are L2-resident after block 0. Same values, same FMA order (c ascending,
// k inner, 4 comps) -> bitwise-identical output (r6 passed @ absmax 0.015625).
__global__ __launch_bounds__(256) void conv_bn1_scan(
        const float* __restrict__ x, const float* __restrict__ w1,
        const float* __restrict__ g1, const float* __restrict__ b1,
        const float* __restrict__ m1, const float* __restrict__ v1,
        float* __restrict__ t) {
    __shared__ float wLDS[CC * BT];                 // 16 KB, [c][k]
    int tid = threadIdx.x;
    #pragma unroll
    for (int r = 0; r < 16; ++r) {
        int dest = r * 256 + tid;                   // contiguous LDS addr
        int k = dest & 31;                          // dest = c*32 + k
        int c = dest >> 5;
        wLDS[dest] = w1[k * CC + c];
    }
    __syncthreads();

    int p4 = blockIdx.x * 1024 + threadIdx.x * 4;   // first pixel of this thread's quad
    int b  = p4 >> 16;
    int ij = p4 & 65535;
    const float4* xb = (const float4*)(x + (size_t)b * (CC * HW) + ij);   // + c*(HW/4)
    float4 acc[BT];
    #pragma unroll
    for (int k = 0; k < BT; ++k) acc[k] = make_float4(0.f, 0.f, 0.f, 0.f);

    #pragma unroll 4
    for (int c = 0; c < CC; ++c) {
        float4 xv = xb[c * (HW / 4)];
        const float* wc = wLDS + c * BT;            // 32 contiguous weights (broadcast)
        #pragma unroll
        for (int k = 0; k < BT; ++k) {
            float wv = wc[k];
            acc[k].x = fmaf(xv.x, wv, acc[k].x);
            acc[k].y = fmaf(xv.y, wv, acc[k].y);
            acc[k].z = fmaf(xv.z, wv, acc[k].z);
            acc[k].w = fmaf(xv.w, wv, acc[k].w);
        }
    }

    // BN1 (must precede the scan: reference scans bn1(conv) output)
    #pragma unroll
    for (int k = 0; k < BT; ++k) {
        float inv = g1[k] * __frsqrt_rn(v1[k] + 1e-5f);
        float add = b1[k] - m1[k] * inv;
        acc[k].x = acc[k].x * inv + add;
        acc[k].y = acc[k].y * inv + add;
        acc[k].z = acc[k].z * inv + add;
        acc[k].w = acc[k].w * inv + add;
    }

    // per-wave row scan: in-thread prefix over 4, then 64-lane shfl scan
    int lane = threadIdx.x & 63;
    float4* tb = (float4*)(t + (size_t)b * (BT * HW) + ij);               // + k*(HW/4)
    #pragma unroll
    for (int k = 0; k < BT; ++k) {
        float4 v = acc[k];
        v.y += v.x; v.z += v.y; v.w += v.z;
        float tot = v.w;
        float sum = tot;
        #pragma unroll
        for (int off = 1; off < 64; off <<= 1) {
            float o = __shfl_up(sum, off, 64);
            if (lane >= off) sum += o;
        }
        float excl = sum - tot;
        v.x += excl; v.y += excl; v.z += excl; v.w += excl;
        tb[k * (HW / 4)] = v;
    }
}

// ---------------- Kernel B2a: per-chunk column partial sums (float4 cols) ----------------
// grid = NPLANE*NCHUNK blocks of 64; thread = column quad (4 cols via float4).
// Per-component accumulate order over r identical to the scalar version -> bitwise same.
__global__ __launch_bounds__(64) void col_partial(const float* __restrict__ t,
                                                  float* __restrict__ T) {
    int plane = blockIdx.x >> 3;
    int chunk = blockIdx.x & 7;
    int q = threadIdx.x;                 // col quad: cols 4q..4q+3
    const float4* tp = (const float4*)(t + (size_t)plane * HW + chunk * CHUNK * WW) + q;
    float4 vals[CHUNK];
    #pragma unroll
    for (int r = 0; r < CHUNK; ++r) vals[r] = tp[r * (WW / 4)];
    float4 s = make_float4(0.f, 0.f, 0.f, 0.f);
    #pragma unroll
    for (int r = 0; r < CHUNK; ++r) {
        s.x += vals[r].x; s.y += vals[r].y; s.z += vals[r].z; s.w += vals[r].w;
    }
    ((float4*)(T + blockIdx.x * 256))[q] = s;
}

// ---------------- Kernel B2b: column scan with chunk offsets -> padded S ----------------
// grid = NPLANE*NCHUNK blocks of 64; thread = column quad. float4 loads of T and h;
// stores to S stay scalar (the +1 padding column misaligns 16B). Per-component
// order identical to the scalar version.
__global__ __launch_bounds__(64) void col_final(const float* __restrict__ t,
                                                const float* __restrict__ T,
                                                float* __restrict__ s) {
    int plane = blockIdx.x >> 3;
    int chunk = blockIdx.x & 7;
    int q = threadIdx.x;                 // col quad: cols 4q..4q+3
    float4 off = make_float4(0.f, 0.f, 0.f, 0.f);
    for (int c = 0; c < chunk; ++c) {
        float4 tv = ((const float4*)(T + (plane * 8 + c) * 256))[q];
        off.x += tv.x; off.y += tv.y; off.z += tv.z; off.w += tv.w;
    }
    const float4* tp = (const float4*)(t + (size_t)plane * HW + chunk * CHUNK * WW) + q;
    float* sp = s + (size_t)plane * SPLANE;
    if (chunk == 0) {                    // top padding row
        #pragma unroll
        for (int e = 0; e < 4; ++e) sp[4 * q + 1 + e] = 0.f;
        if (q == 0) sp[0] = 0.f;
    }
    float4 vals[CHUNK];
    #pragma unroll
    for (int r = 0; r < CHUNK; ++r) vals[r] = tp[r * (WW / 4)];
    float4 run = off;
    int rowbase = chunk * CHUNK;
    #pragma unroll
    for (int r = 0; r < CHUNK; ++r) {
        run.x += vals[r].x; run.y += vals[r].y; run.z += vals[r].z; run.w += vals[r].w;
        float* row = sp + (size_t)(rowbase + r + 1) * SP;
        row[4 * q + 1] = run.x;
        row[4 * q + 2] = run.y;
        row[4 * q + 3] = run.z;
        row[4 * q + 4] = run.w;
        if (q == 0) row[0] = 0.f;        // left padding col
    }
}

// ---------------- Kernel C: box sample via shared D-rows + BN2 + relus ----------------
// grid = B*BT*NBOX*(H/ROWS) blocks; each block produces ROWS=16 output rows.
// Each wave builds 4 D-rows into LDS; each thread then emits 16 elements at
// column j, amortizing horizontal setup + BN2 scalars 16x. The 16 x-values are
// prefetched into registers BEFORE the barrier so their HBM latency hides under
// the D-row build (T14 pattern). Near HBM floor (~313MB traffic).
__global__ __launch_bounds__(256) void box_sample(
        const float* __restrict__ s, const float* __restrict__ x,
        const float* __restrict__ xmin, const float* __restrict__ xmax,
        const float* __restrict__ ymin, const float* __restrict__ ymax,
        const float* __restrict__ g2, const float* __restrict__ b2,
        const float* __restrict__ m2, const float* __restrict__ v2,
        float* __restrict__ out) {
    __shared__ float D[ROWS][SP];
    int bid = blockIdx.x;
    int ig = bid & 15;                   // H/ROWS = 16 row-groups
    int n  = (bid >> 4) & 3;
    int k  = (bid >> 6) & 31;
    int b  = bid >> 11;
    int j  = threadIdx.x;
    int lane = j & 63;
    int wave = j >> 6;
    int kn = k * NBOX + n;
    int ibase = ig * ROWS;
    const float* sp = s + (size_t)(b * BT + k) * SPLANE;

    float xmn = xmin[kn], xmx = xmax[kn], ymn = ymin[kn], ymx = ymax[kn];

    // prefetch x for all 16 rows at this column (independent of D-build)
    int obase = ((b * CC + kn) * HH + ibase) * WW + j;   // < 2^25, fits int
    const float* xp = x + obase;
    float xv[ROWS];
    #pragma unroll
    for (int r = 0; r < ROWS; ++r) xv[r] = __builtin_nontemporal_load(xp + r * WW);

    // Each wave builds D rows {wave, wave+4, wave+8, wave+12}
    #pragma unroll
    for (int rr = 0; rr < 4; ++rr) {
        int r = wave + rr * 4;
        float fi = (float)(ibase + r);
        float u_hi = fminf(fmaxf(fi + xmx, 0.f), 256.f);
        float u_lo = fminf(fmaxf(fi + xmn, 0.f), 256.f);
        int i1 = (int)fminf(floorf(u_hi), 255.f);
        int i0 = (int)fminf(floorf(u_lo), 255.f);
        float wu1 = u_hi - (float)i1;
        float wu0 = u_lo - (float)i0;
        const float* rA = sp + (size_t)i1 * SP;
        const float* rB = rA + SP;
        const float* rC = sp + (size_t)i0 * SP;
        const float* rD = rC + SP;
        #pragma unroll
        for (int tcol = 0; tcol < 4; ++tcol) {
            int c = lane + tcol * 64;
            D[r][c] = rA[c] * (1.f - wu1) + rB[c] * wu1
                    - rC[c] * (1.f - wu0) - rD[c] * wu0;
        }
        if (lane == 0) {
            int c = 256;
            D[r][c] = rA[c] * (1.f - wu1) + rB[c] * wu1
                    - rC[c] * (1.f - wu0) - rD[c] * wu0;
        }
    }
    __syncthreads();

    // horizontal setup: once per thread, reused for all 16 rows
    float v_hi = fminf(fmaxf((float)j + ymx, 0.f), 256.f);
    float v_lo = fminf(fmaxf((float)j + ymn, 0.f), 256.f);
    int j1 = (int)fminf(floorf(v_hi), 255.f);
    int j0 = (int)fminf(floorf(v_lo), 255.f);
    float wv1 = v_hi - (float)j1;
    float wv0 = v_lo - (float)j0;
    float cv1 = 1.f - wv1;
    float cv0 = 1.f - wv0;

    float inv = g2[kn] * __frsqrt_rn(v2[kn] + 1e-3f);
    float scale = inv * __frcp_rn((xmx - xmn) * (ymx - ymn));
    float add = b2[kn] - m2[kn] * inv;

    float* op = out + obase;
    #pragma unroll
    for (int r = 0; r < ROWS; ++r) {
        float hi = D[r][j1] * cv1 + D[r][j1 + 1] * wv1;
        float lo = D[r][j0] * cv0 + D[r][j0 + 1] * wv0;
        float val = (hi - lo) * scale + add;
        val = fmaxf(val, 0.f);                            // relu(bn2)
        __builtin_nontemporal_store(fmaxf(xv[r] + val, 0.f), op + r * WW);
    }
}

extern "C" void kernel_launch(void* const* d_in, const int* in_sizes, int n_in,
                              void* d_out, int out_size, void* d_ws, size_t ws_size,
                              hipStream_t stream) {
    const float* x    = (const float*)d_in[0];
    const float* w1   = (const float*)d_in[1];
    const float* g1   = (const float*)d_in[2];
    const float* b1   = (const float*)d_in[3];
    const float* m1   = (const float*)d_in[4];
    const float* v1   = (const float*)d_in[5];
    const float* xmin = (const float*)d_in[6];
    const float* xmax = (const float*)d_in[7];
    const float* ymin = (const float*)d_in[8];
    const float* ymax = (const float*)d_in[9];
    const float* g2   = (const float*)d_in[10];
    const float* b2   = (const float*)d_in[11];
    const float* m2   = (const float*)d_in[12];
    const float* v2   = (const float*)d_in[13];
    float* out = (float*)d_out;

    float* h = (float*)d_ws;                        // B*BT*HW floats (33.5 MB), row-scanned
    float* S = h + (size_t)BB * BT * HW;            // NPLANE*SPLANE floats (33.8 MB)
    float* T = S + (size_t)NPLANE * SPLANE;         // NPLANE*NCHUNK*256 floats (1 MB)

    conv_bn1_scan<<<(BB * HW) / 1024, 256, 0, stream>>>(x, w1, g1, b1, m1, v1, h);
    col_partial  <<<NPLANE * NCHUNK, 64, 0, stream>>>(h, T);
    col_final    <<<NPLANE * NCHUNK, 64, 0, stream>>>(h, T, S);
    box_sample   <<<BB * BT * NBOX * (HH / ROWS), 256, 0, stream>>>(
                     S, x, xmin, xmax, ymin, ymax, g2, b2, m2, v2, out);
}